// Round 10
// baseline (277.335 us; speedup 1.0000x reference)
//
#include <hip/hip_runtime.h>
#include <math.h>

// VectorQuantizer: argmin_k ||x_n - c_k||^2, N=32768, K=8192, D=64, fp32.
// Round-10: round-9 barrier-free single-wave-block structure with the REAL
// bug fixed. Rounds 8/9 failed identically (absmax 8084, deterministic):
// NOT a sync hazard — dropping xsq makes dist' = csq - 2*dot NEGATIVE for
// most rows, and the final reduce packed RAW float bits into a u64 for an
// unsigned min (raw-bit order is wrong for negative floats). Fix: monotone
// float->unsigned transform (bits<0 ? ~bits : bits|0x80000000) before
// packing. Per-lane tracking already used float compares (correct).
//
// Structure (unchanged from r9): TPB=64 (one wave), BROWS=32 rows,
// grid=1024 (4 blocks/CU via 37.6 KB LDS); each wave DMAs its own 13
// chunks/tile (global_load_lds), waits only on its OWN vmcnt via asm-fenced
// s_waitcnt, no s_barrier in the main loop. 3-plane bf16 split (exact
// residuals), 6 MFMA products in 4 chains, strict < over ascending code +
// u64 (key<<32|code) mins = numpy first-occurrence tie-break.

typedef __attribute__((ext_vector_type(8)))  short s8v;
typedef __attribute__((ext_vector_type(16))) float f16v;

constexpr int NROWS = 32768;
constexpr int KC    = 8192;
constexpr int DD    = 64;
constexpr int BROWS = 32;            // rows per block = per wave (M=32)
constexpr int BTILE = 32;            // codes per tile
constexpr int NT    = KC / BTILE;    // 256
constexpr int TSH     = 6272;        // shorts/tile: 6144 planes + 64 csq + 64 pad
constexpr int CSQ_OFF = 6144;

__device__ __forceinline__ short bf16_rne(float v, float& resid) {
  unsigned u = __float_as_uint(v);
  unsigned r = (u + 0x7FFFu + ((u >> 16) & 1u)) >> 16;
  resid = v - __uint_as_float(r << 16);   // exact
  return (short)r;
}
__device__ __forceinline__ void split3(float v, short& b1, short& b2, short& b3) {
  float r1, r2, r3;
  b1 = bf16_rne(v, r1);
  b2 = bf16_rne(r1, r2);
  b3 = bf16_rne(r2, r3);
}

__device__ __forceinline__ void dma16(const short* g, short* l) {
  __builtin_amdgcn_global_load_lds(
      (const __attribute__((address_space(1))) unsigned int*)g,
      (__attribute__((address_space(3))) unsigned int*)l, 16, 0, 0);
}
__device__ __forceinline__ void dma4(const short* g, short* l) {
  __builtin_amdgcn_global_load_lds(
      (const __attribute__((address_space(1))) unsigned int*)g,
      (__attribute__((address_space(3))) unsigned int*)l, 4, 0, 0);
}

// Pre-kernel: one 64-thread block per 32-code group. Coalesced load of the
// group (8 KB) into LDS, per-lane split3 into the 12 frag-ordered chunks
// (coalesced 16-B stores), csq by lanes<32 (same sequential fmaf chain as
// all passing rounds). Layout mapping identical to the round-6/7 pre-kernel
// (proven): chunk (p,kc) lane (half*32+code) holds plane p of code,
// k = kc*16 + half*8 + j.
__global__ __launch_bounds__(64)
void vq_pre_kernel(const float* __restrict__ cb, short* __restrict__ bSwz) {
  __shared__ float st[BTILE][65];            // +1 pad: conflict-free col reads
  const int g = blockIdx.x;                  // tile / 32-code group
  const int lane = threadIdx.x;

  const float4* src = (const float4*)(cb + (size_t)g * BTILE * DD);
#pragma unroll
  for (int i = 0; i < 8; ++i) {
    const int f = i * 64 + lane;             // float4 index within group
    const float4 v = src[f];
    const int row = f >> 4, c0 = (f & 15) * 4;
    st[row][c0] = v.x; st[row][c0 + 1] = v.y;
    st[row][c0 + 2] = v.z; st[row][c0 + 3] = v.w;
  }
  __syncthreads();

  const int code = lane & 31, half = lane >> 5;
  short* base = bSwz + (size_t)g * TSH;
#pragma unroll
  for (int kc = 0; kc < 4; ++kc) {
    s8v p1, p2, p3;
#pragma unroll
    for (int j = 0; j < 8; ++j) {
      short a, b, c;
      split3(st[code][kc * 16 + half * 8 + j], a, b, c);
      p1[j] = a; p2[j] = b; p3[j] = c;
    }
    *(s8v*)(base + (0 * 4 + kc) * 512 + lane * 8) = p1;
    *(s8v*)(base + (1 * 4 + kc) * 512 + lane * 8) = p2;
    *(s8v*)(base + (2 * 4 + kc) * 512 + lane * 8) = p3;
  }
  if (lane < BTILE) {
    float s = 0.f;
#pragma unroll
    for (int d = 0; d < DD; ++d) s = fmaf(st[lane][d], st[lane][d], s);
    ((float*)(base + CSQ_OFF))[lane] = s;
  }
}

__global__ __launch_bounds__(64) __attribute__((amdgpu_waves_per_eu(1)))
void vq_mfma_kernel(const float* __restrict__ x, const short* __restrict__ bSwz,
                    int* __restrict__ out) {
  __shared__ alignas(16) short ldsB[3][TSH];   // 37,632 B -> 4 blocks/CU

  const int lane = threadIdx.x;
  const int col  = lane & 31;
  const int half = lane >> 5;
  const int blockRow = blockIdx.x * BROWS;

  // ---- A fragments from global, split once: row = blockRow + col,
  // afr[p][kc] = k in [kc*16 + half*8, +8).
  s8v afr[3][4];
  {
    const float* xr = x + (size_t)(blockRow + col) * DD;
#pragma unroll
    for (int kc = 0; kc < 4; ++kc) {
      const float* p8 = xr + kc * 16 + half * 8;
      const float4 a = *(const float4*)p8;
      const float4 b = *(const float4*)(p8 + 4);
      const float v[8] = {a.x, a.y, a.z, a.w, b.x, b.y, b.z, b.w};
      s8v q1, q2, q3;
#pragma unroll
      for (int e = 0; e < 8; ++e) {
        short t1, t2, t3; split3(v[e], t1, t2, t3);
        q1[e] = t1; q2[e] = t2; q3[e] = t3;
      }
      afr[0][kc] = q1; afr[1][kc] = q2; afr[2][kc] = q3;
    }
  }

  short* b0 = &ldsB[0][0];
  short* b1 = &ldsB[1][0];
  short* b2 = &ldsB[2][0];

  // This wave DMAs ALL chunks of its tile: 12 x 1KB + 1 x 256B = 13 issues.
  auto issue_tile = [&](int t, short* buf) {
    const short* g = bSwz + (size_t)t * TSH;
#pragma unroll
    for (int c = 0; c < 12; ++c)
      dma16(g + c * 512 + lane * 8, buf + c * 512 + lane * 8);
    dma4(g + CSQ_OFF + lane * 2, buf + CSQ_OFF + lane * 2);  // csq + pad
  };

  issue_tile(0, b0);
  issue_tile(1, b1);

  const f16v zero16 = {0.f,0.f,0.f,0.f,0.f,0.f,0.f,0.f,
                       0.f,0.f,0.f,0.f,0.f,0.f,0.f,0.f};
  const f16v neg16  = {-1e30f,-1e30f,-1e30f,-1e30f,-1e30f,-1e30f,-1e30f,-1e30f,
                       -1e30f,-1e30f,-1e30f,-1e30f,-1e30f,-1e30f,-1e30f,-1e30f};
  // Two parity sets of 4 chains: [0]=A(kc01) [1]=A(kc23) [2]=B(kc01) [3]=B(kc23).
  f16v S0[4], S1[4];
#pragma unroll
  for (int i = 0; i < 4; ++i) { S0[i] = zero16; S1[i] = neg16; }
  float csOld = 0.f;
  float bestD[16];
  unsigned bestC[16];
#pragma unroll
  for (int i = 0; i < 16; ++i) { bestD[i] = __builtin_inff(); bestC[i] = 0u; }

  // Chain A products: a1b1, a2b1, a2b2 ; chain B: a1b2, a1b3, a3b1.
  constexpr int PAA[3] = {0, 1, 1}, PBA[3] = {0, 0, 1};
  constexpr int PAB[3] = {0, 0, 2}, PBB[3] = {1, 2, 0};

  // Tile body: [own-vmcnt wait (fenced)][12 frag ds_reads + csq]
  // [24 MFMA into W][DMA t+2][pipelined epi(t-1) from R]. No barrier.
  // At the wait: outstanding = 26 (tiles t, t+1); vmcnt(13) drains tile t.
  auto body = [&](int t, short* bufR, short* bufW, f16v* W, const f16v* R) {
    asm volatile("s_waitcnt vmcnt(13)" ::: "memory");

    const float csNew = ((const float*)(bufR + CSQ_OFF))[col];
    s8v f[3][4];
#pragma unroll
    for (int p = 0; p < 3; ++p)
#pragma unroll
      for (int kc = 0; kc < 4; ++kc)
        f[p][kc] = *(const s8v*)(bufR + (p * 4 + kc) * 512 + lane * 8);

#pragma unroll
    for (int i = 0; i < 4; ++i) W[i] = zero16;
#pragma unroll
    for (int u = 0; u < 2; ++u)
#pragma unroll
      for (int pr = 0; pr < 3; ++pr) {
        W[0] = __builtin_amdgcn_mfma_f32_32x32x16_bf16(
            afr[PAA[pr]][u],     f[PBA[pr]][u],     W[0], 0, 0, 0);
        W[1] = __builtin_amdgcn_mfma_f32_32x32x16_bf16(
            afr[PAA[pr]][2 + u], f[PBA[pr]][2 + u], W[1], 0, 0, 0);
        W[2] = __builtin_amdgcn_mfma_f32_32x32x16_bf16(
            afr[PAB[pr]][u],     f[PBB[pr]][u],     W[2], 0, 0, 0);
        W[3] = __builtin_amdgcn_mfma_f32_32x32x16_bf16(
            afr[PAB[pr]][2 + u], f[PBB[pr]][2 + u], W[3], 0, 0, 0);
      }

    issue_tile((t + 2) & (NT - 1), bufW);   // wrap keeps vmcnt FIFO uniform

    // Epilogue for tile t-1 (t=0: R=-1e30 -> dist ~ +8e30, displaced by any
    // real tile; bogus phantom code is overwritten then).
    const unsigned codeBase = (unsigned)((t - 1) * BTILE + col);
#pragma unroll
    for (int i = 0; i < 16; ++i) {
      const float acc = (R[0][i] + R[1][i]) + (R[2][i] + R[3][i]);
      const float dist = fmaf(-2.f, acc, csOld);  // xsq dropped: may be <0,
      if (dist < bestD[i]) { bestD[i] = dist; bestC[i] = codeBase; }
    }                                             // float cmp handles sign.
    csOld = csNew;
  };

  for (int t = 0; t < NT; t += 2) {
    body(t, b0, b2, S0, S1);
    short* tmp0 = b0; b0 = b1; b1 = b2; b2 = tmp0;
    body(t + 1, b0, b2, S1, S0);
    short* tmp1 = b0; b0 = b1; b1 = b2; b2 = tmp1;
  }
  // Final epilogue for tile NT-1 (its accs are in S1).
  {
    const unsigned codeBase = (unsigned)((NT - 1) * BTILE + col);
#pragma unroll
    for (int i = 0; i < 16; ++i) {
      const float acc = (S1[0][i] + S1[1][i]) + (S1[2][i] + S1[3][i]);
      const float dist = fmaf(-2.f, acc, csOld);
      if (dist < bestD[i]) { bestD[i] = dist; bestC[i] = codeBase; }
    }
  }

  // Drain wrap-around DMAs before the wave can exit (LDS-DMA landing after
  // s_endpgm could corrupt a successor workgroup's LDS).
  asm volatile("s_waitcnt vmcnt(0)" ::: "memory");

  // ---- Cross-lane reduce. THE FIX: dist may be negative, so map float
  // bits through the monotone total-order transform before packing
  // (negatives: ~bits reverses their descending raw order and places them
  // below positives; positives: set MSB). Equal dists -> equal keys -> u64
  // min picks the lowest code = numpy first-occurrence.
  unsigned long long key[16];
#pragma unroll
  for (int i = 0; i < 16; ++i) {
    unsigned sb = __float_as_uint(bestD[i]);
    sb = (sb & 0x80000000u) ? ~sb : (sb | 0x80000000u);
    key[i] = ((unsigned long long)sb << 32) | bestC[i];
  }
#pragma unroll
  for (int i = 0; i < 16; ++i) {
#pragma unroll
    for (int m = 1; m < 32; m <<= 1) {
      const unsigned long long o = __shfl_xor(key[i], m, 64);
      if (o < key[i]) key[i] = o;
    }
  }
  if (col == 0) {
#pragma unroll
    for (int i = 0; i < 16; ++i) {
      const int row = (i & 3) + 8 * (i >> 2) + 4 * half;
      out[blockRow + row] = (int)(unsigned)(key[i] & 0xFFFFFFFFull);
    }
  }
}

extern "C" void kernel_launch(void* const* d_in, const int* in_sizes, int n_in,
                              void* d_out, int out_size, void* d_ws, size_t ws_size,
                              hipStream_t stream) {
  const float* x  = (const float*)d_in[0];   // [N, 64] fp32
  const float* cb = (const float*)d_in[1];   // [K, 64] fp32
  int* out = (int*)d_out;                    // [N] int32

  short* bSwz = (short*)d_ws;                // 256 tiles x 12,544 B = 3.06 MB

  vq_pre_kernel<<<dim3(NT), dim3(64), 0, stream>>>(cb, bSwz);
  vq_mfma_kernel<<<dim3(NROWS / BROWS), dim3(64), 0, stream>>>(x, bSwz, out);
}